// Round 17
// baseline (516.515 us; speedup 1.0000x reference)
//
#include <hip/hip_runtime.h>
#include <math.h>

#define NTOK 16384
#define KD   2048
#define NE   256
#define BM   32
#define NSTEP 64              // K-steps of 32
#define EPS  2.5e-4f

using bf16x8 = __attribute__((ext_vector_type(8))) short;
using f32x16 = __attribute__((ext_vector_type(16))) float;
using u16 = unsigned short;
using u32 = unsigned int;

__device__ __forceinline__ u16 f2bf(float x) {
    u32 u = __float_as_uint(x);
    return (u16)((u + 0x7FFFu + ((u >> 16) & 1u)) >> 16);
}
__device__ __forceinline__ float bf2f(u16 h) {
    return __uint_as_float(((u32)h) << 16);
}

// ---- K0: split W into bf16 hi/lo, MFMA-fragment-ordered image.
// dst_u16 = (c*2+s)*4096 + wv*1024 + nf*512 + kh*256 + em*8 + (k&7)
__global__ __launch_bounds__(256) void wsplit_kernel(
    const float* __restrict__ wgt, u16* __restrict__ Whi, u16* __restrict__ Wlo)
{
    const int idx = blockIdx.x * 256 + threadIdx.x;   // e*256 + ko
    const int e  = idx >> 8;
    const int ko = idx & 255;                          // k-octet
    const int k  = ko * 8;
    const int c  = k >> 5, s = (k >> 4) & 1, kh = (k >> 3) & 1;
    const int dst = (c * 2 + s) * 4096 + (e >> 6) * 1024 + ((e >> 5) & 1) * 512
                  + kh * 256 + (e & 31) * 8;
    const float* p = wgt + (size_t)e * KD + k;
    u16 hi[8], lo[8];
#pragma unroll
    for (int i = 0; i < 8; ++i) {
        const float w = p[i];
        hi[i] = f2bf(w);
        lo[i] = f2bf(w - bf2f(hi[i]));
    }
    *(uint4*)(Whi + dst) = *(const uint4*)hi;
    *(uint4*)(Wlo + dst) = *(const uint4*)lo;
}

typedef __attribute__((address_space(1))) const void GV;
typedef __attribute__((address_space(3))) void LV;
__device__ __forceinline__ void gld_lds16(const void* g, void* l) {
    __builtin_amdgcn_global_load_lds((GV*)g, (LV*)l, 16, 0, 0);
}

#define MFMA32(A, B, C) __builtin_amdgcn_mfma_f32_32x32x16_bf16((A), (B), (C), 0, 0, 0)

// ---- K1: MFMA split-GEMM; B staged via global_load_lds (no VGPR cost) ----
__global__ __launch_bounds__(256) void gate_kernel(
    const float* __restrict__ hid, const u16* __restrict__ Whi, const u16* __restrict__ Wlo,
    float* __restrict__ out, float* __restrict__ cnt, float* __restrict__ prb,
    int* __restrict__ flagcnt, int* __restrict__ flaglist)
{
    __shared__ union {
        struct { u16 bh[2][8192]; u16 bl[2][8192]; } st;   // 64 KB B dbuf
        float ls[BM][257];
    } sh;
    __shared__ u16 ah[2][BM][40], al[2][BM][40];
    __shared__ float maxS[BM], sumS[BM], invS[BM];

    const int tid  = threadIdx.x;
    const int lane = tid & 63;
    const int wv   = tid >> 6;
    const int ln31 = lane & 31;
    const int kh8  = (lane >> 5) * 8;
    const int t0   = blockIdx.x * BM;

    f32x16 acc[2];
#pragma unroll
    for (int nf = 0; nf < 2; ++nf)
#pragma unroll
        for (int r = 0; r < 16; ++r) acc[nf][r] = 0.f;

    // A staging: thread -> (token, k-quad)
    float4 areg;
    const int am = tid >> 3;           // token 0..31
    const int ak = (tid & 7) * 4;      // k 0..28

    auto loadA = [&](int c) {
        areg = *(const float4*)(hid + (size_t)(t0 + am) * KD + c * 32 + ak);
    };
    auto writeA = [&](int buf) {
        float f[4] = {areg.x, areg.y, areg.z, areg.w};
#pragma unroll
        for (int i = 0; i < 4; ++i) {
            const u16 hi = f2bf(f[i]);
            ah[buf][am][ak + i] = hi;
            al[buf][am][ak + i] = f2bf(f[i] - bf2f(hi));
        }
    };
    auto stageB = [&](int c, int buf) {    // 8 fire-and-forget DMA ops
        const u16* srch = Whi + (size_t)c * 8192 + tid * 8;
        const u16* srcl = Wlo + (size_t)c * 8192 + tid * 8;
        u16* dsth = &sh.st.bh[buf][tid * 8];
        u16* dstl = &sh.st.bl[buf][tid * 8];
#pragma unroll
        for (int seg = 0; seg < 4; ++seg) {
            gld_lds16(srch + seg * 2048, dsth + seg * 2048);
            gld_lds16(srcl + seg * 2048, dstl + seg * 2048);
        }
    };

    loadA(0); stageB(0, 0); writeA(0);
    int cur = 0;

#pragma unroll 1
    for (int c = 0; c < NSTEP; ++c) {
        __syncthreads();                    // bs[cur]/A[cur] ready; [nxt] free
        const int nxt = cur ^ 1;
        if (c + 1 < NSTEP) { loadA(c + 1); stageB(c + 1, nxt); }

#pragma unroll
        for (int s = 0; s < 2; ++s) {
            const int boff = s * 4096 + wv * 1024 + lane * 8;
            const bf16x8 bh0 = *(const bf16x8*)&sh.st.bh[cur][boff];
            const bf16x8 bl0 = *(const bf16x8*)&sh.st.bl[cur][boff];
            const bf16x8 bh1 = *(const bf16x8*)&sh.st.bh[cur][boff + 512];
            const bf16x8 bl1 = *(const bf16x8*)&sh.st.bl[cur][boff + 512];
            const bf16x8 a_h = *(const bf16x8*)&ah[cur][ln31][s * 16 + kh8];
            const bf16x8 a_l = *(const bf16x8*)&al[cur][ln31][s * 16 + kh8];

            acc[0] = MFMA32(a_h, bh0, acc[0]);
            acc[0] = MFMA32(a_h, bl0, acc[0]);
            acc[0] = MFMA32(a_l, bh0, acc[0]);
            acc[1] = MFMA32(a_h, bh1, acc[1]);
            acc[1] = MFMA32(a_h, bl1, acc[1]);
            acc[1] = MFMA32(a_l, bh1, acc[1]);
        }
        if (c + 1 < NSTEP) writeA(nxt);
        cur = nxt;
    }

    // ---- dump logits (C/D: col=lane&31, row=(r&3)+8*(r>>2)+4*(lane>>5)) ----
    __syncthreads();
#pragma unroll
    for (int nf = 0; nf < 2; ++nf) {
        const int col = wv * 64 + nf * 32 + ln31;
#pragma unroll
        for (int r = 0; r < 16; ++r) {
            const int row = (r & 3) + 8 * (r >> 2) + 4 * (lane >> 5);
            sh.ls[row][col] = acc[nf][r];
        }
    }
    if (tid < BM) sumS[tid] = 0.f;
    __syncthreads();

    // ---- per-token top-k + margin flags (threads 0..31) ----
    if (tid < BM) {
        const float* lr = &sh.ls[tid][0];
        float tv[9]; int ti[9];
#pragma unroll
        for (int j = 0; j < 9; ++j) { tv[j] = -1e30f; ti[j] = 0; }
        float gv3[8], gv4[8];
        float rowmax = -1e30f;

        auto ins9 = [&](float v, int idx) {
#pragma unroll
            for (int p = 0; p < 9; ++p) {
                if (v > tv[p]) {
#pragma unroll
                    for (int q = 8; q > p; --q) { tv[q] = tv[q - 1]; ti[q] = ti[q - 1]; }
                    tv[p] = v; ti[p] = idx;
                    break;
                }
            }
        };

#pragma unroll 1
        for (int g = 0; g < 8; ++g) {
            float v0 = -1e30f, v1 = -1e30f, v2 = -1e30f, v3 = -1e30f, v4 = -1e30f;
            int   i0 = 0, i1 = 0, i2 = 0, i3 = 0;
            for (int j = 0; j < 32; ++j) {
                const float v = lr[g * 32 + j];
                if (v > v0)      { v4=v3; v3=v2;i3=i2; v2=v1;i2=i1; v1=v0;i1=i0; v0=v;i0=j; }
                else if (v > v1) { v4=v3; v3=v2;i3=i2; v2=v1;i2=i1; v1=v;i1=j; }
                else if (v > v2) { v4=v3; v3=v2;i3=i2; v2=v;i2=j; }
                else if (v > v3) { v4=v3; v3=v;i3=j; }
                else if (v > v4) { v4=v; }
            }
            rowmax = fmaxf(rowmax, v0);
            gv3[g] = v3; gv4[g] = v4;
            ins9(v0, g * 32 + i0);
            ins9(v1, g * 32 + i1);
            ins9(v2, g * 32 + i2);
            ins9(v3, g * 32 + i3);
        }

        bool flag = false;
#pragma unroll
        for (int r = 0; r < 8; ++r)
            if (tv[r] - tv[r + 1] < EPS) flag = true;
#pragma unroll
        for (int g = 0; g < 8; ++g)
            if (gv3[g] - gv4[g] < EPS && gv3[g] > tv[7] - EPS) flag = true;

        const float s01 = __fadd_rn(tv[0], tv[1]);
        const float s23 = __fadd_rn(tv[2], tv[3]);
        const float s45 = __fadd_rn(tv[4], tv[5]);
        const float s67 = __fadd_rn(tv[6], tv[7]);
        float s = __fadd_rn(__fadd_rn(s01, s23), __fadd_rn(s45, s67));
        s = __fadd_rn(s, 1e-20f);

        const size_t tg2 = (size_t)(t0 + tid);
#pragma unroll
        for (int j = 0; j < 8; ++j) {
            out[tg2 * 8 + j]                    = (float)ti[j];
            out[(size_t)NTOK * 8 + tg2 * 8 + j] = __fdiv_rn(tv[j], s);
            atomicAdd(&cnt[ti[j]], 1.0f);
        }
        if (flag) {
            const int fi = atomicAdd(flagcnt, 1);
            flaglist[fi] = t0 + tid;
        }
        maxS[tid] = rowmax;
    }
    __syncthreads();

    // ---- softmax denominator (8 threads per token) ----
    {
        const int t  = tid >> 3;
        const int c0 = (tid & 7) * 32;
        const float m = maxS[t];
        float part = 0.f;
#pragma unroll
        for (int j = 0; j < 32; ++j) part += __expf(sh.ls[t][c0 + j] - m);
        atomicAdd(&sumS[t], part);
    }
    __syncthreads();
    if (tid < BM) invS[tid] = 1.0f / sumS[tid];
    __syncthreads();

    // ---- per-expert softmax-prob partial over block tokens ----
    {
        float p = 0.f;
#pragma unroll
        for (int n = 0; n < BM; ++n) p += __expf(sh.ls[n][tid] - maxS[n]) * invS[n];
        atomicAdd(&prb[tid], p);
    }
}

// ---- K2: bit-exact numpy-DAG recompute of flagged tokens (grid-stride) ----
__global__ __launch_bounds__(256) void exact_kernel(
    const float* __restrict__ hid, const float* __restrict__ wgt,
    float* __restrict__ out, float* __restrict__ cnt,
    const int* __restrict__ flagcnt, const int* __restrict__ flaglist)
{
    const int fn = *flagcnt;

    __shared__ float wch[256 * 17];
    __shared__ float hch[8 * 17];
    __shared__ float exls[8][257];
    __shared__ int tk[8];

    const int tid = threadIdx.x;
    const int tg  = tid >> 7;            // 0..1 (4 tokens each)
    const int eg  = (tid >> 2) & 31;     // 0..31
    const int l   = tid & 3;

#pragma unroll 1
    for (int base = blockIdx.x * 8; base < fn; base += gridDim.x * 8) {
        const int nt = min(8, fn - base);
        __syncthreads();
        if (tid < 8) tk[tid] = (tid < nt) ? flaglist[base + tid] : flaglist[base];
        __syncthreads();

        float accq[4][8];
#pragma unroll
        for (int i = 0; i < 4; ++i)
#pragma unroll
            for (int j = 0; j < 8; ++j) accq[i][j] = 0.f;

#pragma unroll 1
        for (int c = 0; c < 128; ++c) {      // 16-blocks ascending
            __syncthreads();
            {
                const float* p = wgt + (size_t)tid * KD + c * 16;
                float4 w0 = *(const float4*)(p);
                float4 w1 = *(const float4*)(p + 4);
                float4 w2 = *(const float4*)(p + 8);
                float4 w3 = *(const float4*)(p + 12);
                float* wr = &wch[tid * 17];
                wr[0]=w0.x; wr[1]=w0.y; wr[2]=w0.z; wr[3]=w0.w;
                wr[4]=w1.x; wr[5]=w1.y; wr[6]=w1.z; wr[7]=w1.w;
                wr[8]=w2.x; wr[9]=w2.y; wr[10]=w2.z; wr[11]=w2.w;
                wr[12]=w3.x; wr[13]=w3.y; wr[14]=w3.z; wr[15]=w3.w;
            }
            if (tid < 128) {
                const int tok = tid >> 4, k = tid & 15;
                hch[tok * 17 + k] = hid[(size_t)tk[tok] * KD + c * 16 + k];
            }
            __syncthreads();

#pragma unroll
            for (int q = 3; q >= 0; --q) {
                const int k = 4 * q + l;
                float hv[4], wv2[8];
#pragma unroll
                for (int i = 0; i < 4; ++i) hv[i] = hch[(tg * 4 + i) * 17 + k];
#pragma unroll
                for (int j = 0; j < 8; ++j) wv2[j] = wch[(j * 32 + eg) * 17 + k];
#pragma unroll
                for (int i = 0; i < 4; ++i)
#pragma unroll
                    for (int j = 0; j < 8; ++j)
                        accq[i][j] = __fadd_rn(__fmul_rn(hv[i], wv2[j]), accq[i][j]);
            }
        }

        __syncthreads();
#pragma unroll
        for (int i = 0; i < 4; ++i)
#pragma unroll
            for (int j = 0; j < 8; ++j) {
                float v = accq[i][j];
                v = __fadd_rn(v, __shfl_xor(v, 1));
                v = __fadd_rn(v, __shfl_xor(v, 2));
                if (l == 0) exls[tg * 4 + i][j * 32 + eg] = v;
            }
        __syncthreads();

        if (tid < nt) {
            const float* lr = &exls[tid][0];
            float tv[8]; int ti[8];
#pragma unroll
            for (int j = 0; j < 8; ++j) { tv[j] = -1e30f; ti[j] = 0; }

            auto ins8 = [&](float v, int idx) {
#pragma unroll
                for (int p = 0; p < 8; ++p) {
                    if (v > tv[p]) {
#pragma unroll
                        for (int q = 7; q > p; --q) { tv[q] = tv[q - 1]; ti[q] = ti[q - 1]; }
                        tv[p] = v; ti[p] = idx;
                        break;
                    }
                }
            };

#pragma unroll 1
            for (int g = 0; g < 8; ++g) {
                float v0 = -1e30f, v1 = -1e30f, v2 = -1e30f, v3 = -1e30f;
                int   i0 = 0, i1 = 0, i2 = 0, i3 = 0;
                for (int j = 0; j < 32; ++j) {
                    const float v = lr[g * 32 + j];
                    if (v > v0)      { v3=v2;i3=i2; v2=v1;i2=i1; v1=v0;i1=i0; v0=v;i0=j; }
                    else if (v > v1) { v3=v2;i3=i2; v2=v1;i2=i1; v1=v;i1=j; }
                    else if (v > v2) { v3=v2;i3=i2; v2=v;i2=j; }
                    else if (v > v3) { v3=v;i3=j; }
                }
                ins8(v0, g * 32 + i0);
                ins8(v1, g * 32 + i1);
                ins8(v2, g * 32 + i2);
                ins8(v3, g * 32 + i3);
            }

            const float s01 = __fadd_rn(tv[0], tv[1]);
            const float s23 = __fadd_rn(tv[2], tv[3]);
            const float s45 = __fadd_rn(tv[4], tv[5]);
            const float s67 = __fadd_rn(tv[6], tv[7]);
            float s = __fadd_rn(__fadd_rn(s01, s23), __fadd_rn(s45, s67));
            s = __fadd_rn(s, 1e-20f);

            const size_t gt = (size_t)tk[tid];
#pragma unroll
            for (int j = 0; j < 8; ++j) {
                const int oldi = (int)out[gt * 8 + j];
                if (oldi != ti[j]) {
                    atomicAdd(&cnt[oldi], -1.0f);
                    atomicAdd(&cnt[ti[j]], 1.0f);
                }
                out[gt * 8 + j]                    = (float)ti[j];
                out[(size_t)NTOK * 8 + gt * 8 + j] = __fdiv_rn(tv[j], s);
            }
        }
        __syncthreads();
    }
}

__global__ void aux_kernel(const float* __restrict__ cnt,
                           const float* __restrict__ prb,
                           float* __restrict__ out)
{
    const int tid = threadIdx.x;
    float v = cnt[tid] * prb[tid];
#pragma unroll
    for (int off = 32; off; off >>= 1) v += __shfl_down(v, off, 64);
    __shared__ float ps[4];
    if ((tid & 63) == 0) ps[tid >> 6] = v;
    __syncthreads();
    if (tid == 0) {
        const float tot = ps[0] + ps[1] + ps[2] + ps[3];
        out[(size_t)NTOK * 8 * 2] = tot * (0.001f / (131072.0f * 16384.0f));
    }
}

extern "C" void kernel_launch(void* const* d_in, const int* in_sizes, int n_in,
                              void* d_out, int out_size, void* d_ws, size_t ws_size,
                              hipStream_t stream)
{
    (void)in_sizes; (void)n_in; (void)out_size; (void)ws_size;
    const float* hid = (const float*)d_in[0];
    const float* wgt = (const float*)d_in[1];
    float* out = (float*)d_out;

    float* cnt      = (float*)d_ws;                  // 256 f
    float* prb      = cnt + NE;                      // 256 f
    int*   flagcnt  = (int*)(prb + NE);              // 1 i (+63 pad)
    int*   flaglist = flagcnt + 64;                  // 16384 i
    u16*   Whi      = (u16*)(flaglist + NTOK);       // 1 MB
    u16*   Wlo      = Whi + (size_t)NE * KD;         // 1 MB

    hipMemsetAsync(d_ws, 0, (2 * NE + 64) * sizeof(float), stream);
    wsplit_kernel<<<NE * KD / 8 / 256, 256, 0, stream>>>(wgt, Whi, Wlo);
    gate_kernel<<<NTOK / BM, 256, 0, stream>>>(hid, Whi, Wlo, out, cnt, prb, flagcnt, flaglist);
    exact_kernel<<<256, 256, 0, stream>>>(hid, wgt, out, cnt, flagcnt, flaglist);
    aux_kernel<<<1, 256, 0, stream>>>(cnt, prb, out);
}